// Round 6
// baseline (421.884 us; speedup 1.0000x reference)
//
#include <hip/hip_runtime.h>
#include <math.h>

static constexpr float kNegSlope = 0.2f;
static constexpr float kEps = 1e-16f;
static constexpr int SLICES = 256;   // partition slices for hist/bin passes
static constexpr int BSHIFT = 7;     // 128 nodes per bucket
static constexpr int BMASK = 127;
static constexpr unsigned SRCMASK = 0x1FFFFu;  // 17 bits (N < 131072)

__device__ __forceinline__ float leaky(float v) {
    return v > 0.0f ? v : kNegSlope * v;
}

// ================= atomic-free bucketed partition (PROVEN R3 form) =================
// R4's global-atomic scatter was a disaster (134us, 107MB WRITE_SIZE: 16x
// amplification of random 4B writes across non-coherent XCD L2s). Reverted
// verbatim. bucket = dst >> 7. Per-slice LDS histograms -> scan of
// table[bucket][slice] -> deterministic scatter with LDS cursors; writes are
// bucket-cursor-sequential (clustered), which is what keeps WRITE_SIZE sane.
// Record: src | (d&127)<<17 (24 bits, 4B).

__global__ __launch_bounds__(512) void k_hist1(const int* __restrict__ ei,
                                               int* __restrict__ table,
                                               int E, int NBUCK) {
    __shared__ int hist[832];
    int b = blockIdx.x, t = threadIdx.x;
    for (int i = t; i < NBUCK; i += 512) hist[i] = 0;
    __syncthreads();
    int S = (((E + SLICES - 1) / SLICES) + 3) & ~3;  // slice size, multiple of 4
    int lo = b * S, hi = min(lo + S, E);
    for (int i = lo + t * 4; i < hi; i += 512 * 4) {
        int4 dv = *(const int4*)(ei + E + i);
        atomicAdd(&hist[dv.x >> BSHIFT], 1);
        atomicAdd(&hist[dv.y >> BSHIFT], 1);
        atomicAdd(&hist[dv.z >> BSHIFT], 1);
        atomicAdd(&hist[dv.w >> BSHIFT], 1);
    }
    __syncthreads();
    for (int i = t; i < NBUCK; i += 512) table[i * SLICES + b] = hist[i];
}

// Scan pass 1: block b sums its 1024-int chunk -> partial[b].
__global__ __launch_bounds__(256) void k_scan_reduce(const int* __restrict__ src,
                                                     int* __restrict__ partial, int n) {
    __shared__ int wsum[4];
    int b = blockIdx.x, t = threadIdx.x;
    int base = b * 1024 + t * 4;
    int s = 0;
#pragma unroll
    for (int k = 0; k < 4; ++k) {
        int idx = base + k;
        s += (idx < n) ? src[idx] : 0;
    }
#pragma unroll
    for (int off = 1; off < 64; off <<= 1) s += __shfl_xor(s, off);
    if ((t & 63) == 0) wsum[t >> 6] = s;
    __syncthreads();
    if (t == 0) partial[b] = wsum[0] + wsum[1] + wsum[2] + wsum[3];
}

// Scan pass 2: block b computes its chunk base by reducing partial[i<b],
// then wave-scans its 1024-int chunk in place (exclusive).
__global__ __launch_bounds__(256) void k_scan_apply(int* __restrict__ data,
                                                    const int* __restrict__ partial,
                                                    int n, int nsb) {
    __shared__ int sm[8];
    __shared__ int baseSh;
    int b = blockIdx.x, t = threadIdx.x;
    int acc = 0;
    for (int i = t; i < b; i += 256) acc += partial[i];
#pragma unroll
    for (int off = 1; off < 64; off <<= 1) acc += __shfl_xor(acc, off);
    if ((t & 63) == 0) sm[t >> 6] = acc;
    __syncthreads();
    if (t == 0) baseSh = sm[0] + sm[1] + sm[2] + sm[3];
    __syncthreads();
    int chunkBase = baseSh;
    __syncthreads();  // sm reused below
    int base = b * 1024 + t * 4;
    int v[4];
#pragma unroll
    for (int k = 0; k < 4; ++k) {
        int idx = base + k;
        v[k] = (idx < n) ? data[idx] : 0;
    }
    int sum4 = v[0] + v[1] + v[2] + v[3];
    int s = sum4;
#pragma unroll
    for (int off = 1; off < 64; off <<= 1) {
        int u = __shfl_up(s, off);
        if ((t & 63) >= off) s += u;
    }
    if ((t & 63) == 63) sm[t >> 6] = s;
    __syncthreads();
    int woff = 0;
    int w = t >> 6;
    for (int ww = 0; ww < w; ++ww) woff += sm[ww];
    int ex = chunkBase + woff + (s - sum4);
#pragma unroll
    for (int k = 0; k < 4; ++k) {
        int idx = base + k;
        if (idx < n) data[idx] = ex;
        ex += v[k];
    }
}

__global__ __launch_bounds__(512) void k_bin2(const int* __restrict__ ei,
                                              const int* __restrict__ table,
                                              unsigned* __restrict__ sbuf, int E, int NBUCK) {
    __shared__ int cur[832];
    int b = blockIdx.x, t = threadIdx.x;
    for (int i = t; i < NBUCK; i += 512) cur[i] = table[i * SLICES + b];
    __syncthreads();
    int S = (((E + SLICES - 1) / SLICES) + 3) & ~3;
    int lo = b * S, hi = min(lo + S, E);
    for (int i = lo + t * 4; i < hi; i += 512 * 4) {
        int4 sv = *(const int4*)(ei + i);
        int4 dv = *(const int4*)(ei + E + i);
        int pos;
        pos = atomicAdd(&cur[dv.x >> BSHIFT], 1);
        sbuf[pos] = (unsigned)sv.x | ((unsigned)(dv.x & BMASK) << 17);
        pos = atomicAdd(&cur[dv.y >> BSHIFT], 1);
        sbuf[pos] = (unsigned)sv.y | ((unsigned)(dv.y & BMASK) << 17);
        pos = atomicAdd(&cur[dv.z >> BSHIFT], 1);
        sbuf[pos] = (unsigned)sv.z | ((unsigned)(dv.z & BMASK) << 17);
        pos = atomicAdd(&cur[dv.w >> BSHIFT], 1);
        sbuf[pos] = (unsigned)sv.w | ((unsigned)(dv.w & BMASK) << 17);
    }
}

// ================= layer 1: per-bucket EDGE-PARALLEL attention =================
// R5 redesign: bucket-grouped records (src | d<<17) already carry the local
// dst — per-node CSR is unnecessary. k_sort DELETED (~12us + 12.8MB traffic).
// One block per bucket; 8 lanes/record (lane = head): 1 exp + 3 LDS-atomic
// adds into acc[head][132-stride] (banks spread; per-CU, no coherence traffic
// — nothing like R4's global-atomic scatter). Perfectly load-balanced: no
// per-node loop divergence, no tails, no 24-value shuffle reduce (R2 showed
// the reduce was half of gather1's instructions).
// Straight-line softmax (no max): inputs N(0,1)-scale, |e|<~8 — validated
// R8-R18. k_fold does the dense W1->relu->W2.
__global__ __launch_bounds__(512) void k_att1(
        const unsigned* __restrict__ sbuf, const int* __restrict__ table,
        const float* __restrict__ x,
        const float* __restrict__ W1, const float* __restrict__ att_src1,
        const float* __restrict__ att_dst1,
        float* __restrict__ attA, float* __restrict__ attB,
        int N, int E, int NBUCK) {
    __shared__ float pbuf[32];    // Ps d0 | Ps d1 | Pd d0 | Pd d1 (8 heads each)
    __shared__ float adv[1056];   // [h][d], stride 132 -> bank (4h+d)%32
    __shared__ float accL[1056];
    __shared__ float accS0[1056];
    __shared__ float accS1[1056];
    int b = blockIdx.x, t = threadIdx.x;
    int base = b << BSHIFT;
    if (t < 32) {  // rank-2 projections
        int which = t >> 4;   // 0=src, 1=dst
        int hd = t & 15;
        int h = hd >> 1, d = hd & 1;
        const float* att = which ? att_dst1 : att_src1;
        float s = 0.0f;
#pragma unroll
        for (int c = 0; c < 16; ++c) s += W1[d * 128 + h * 16 + c] * att[h * 16 + c];
        pbuf[which * 16 + d * 8 + h] = s;
    }
    for (int i = t; i < 1056; i += 512) {
        accL[i] = 0.f; accS0[i] = 0.f; accS1[i] = 0.f;
    }
    __syncthreads();
    const float2* x2 = (const float2*)x;
    for (int e = t; e < 1024; e += 512) {   // adv[h][d] = x[base+d] . Pd[h]
        int h = e >> 7, d = e & 127;
        int n = base + d;
        float2 xn = (n < N) ? x2[n] : make_float2(0.f, 0.f);
        adv[h * 132 + d] = xn.x * pbuf[16 + h] + xn.y * pbuf[24 + h];
    }
    __syncthreads();
    int lo = table[b * SLICES];
    int hi = (b + 1 < NBUCK) ? table[(b + 1) * SLICES] : E;
    int h = t & 7;
    float Ps0 = pbuf[h], Ps1 = pbuf[8 + h];
    for (int j = lo + (t >> 3); j < hi; j += 64) {  // 64 records per block-pass
        unsigned v = sbuf[j];                        // 8-lane broadcast
        int src = (int)(v & SRCMASK);
        int d = (int)(v >> 17);
        float2 xs = x2[src];                         // cache-hot (800KB)
        float p = __expf(leaky(fmaf(xs.x, Ps0, fmaf(xs.y, Ps1, adv[h * 132 + d]))));
        int o = h * 132 + d;
        atomicAdd(&accL[o], p);
        atomicAdd(&accS0[o], p * xs.x);
        atomicAdd(&accS1[o], p * xs.y);
    }
    __syncthreads();
    for (int e = t; e < 1024; e += 512) {  // coalesced: attA[base*8 + e]
        int d = e >> 3, hh = e & 7;
        int n = base + d;
        if (n < N) {
            int o = hh * 132 + d;
            float inv = 1.0f / (accL[o] + kEps);
            attA[n * 8 + hh] = accS0[o] * inv;
            attB[n * 8 + hh] = accS1[o] * inv;
        }
    }
}

// ================= dense per-node MLP: W1 -> relu -> W2 =================
// 1 thread/node. Weights packed into two float4 LDS tables (uniform-address
// broadcast reads, conflict-free).
__global__ __launch_bounds__(256) void k_fold(
        const float* __restrict__ attA, const float* __restrict__ attB,
        const float* __restrict__ W1, const float* __restrict__ b1,
        const float* __restrict__ W2, float* __restrict__ h2, int N) {
    __shared__ float4 pk1[128];  // (W1a, W1b, b1, 0) per col
    __shared__ float4 pk2[128];  // W2 row per col
    int t = threadIdx.x;
    if (t < 128) {
        pk1[t] = make_float4(W1[t], W1[128 + t], b1[t], 0.f);
        pk2[t] = ((const float4*)W2)[t];
    }
    __syncthreads();
    int n = blockIdx.x * 256 + t;
    if (n >= N) return;
    const float4* A = (const float4*)(attA + n * 8);
    const float4* B = (const float4*)(attB + n * 8);
    float4 a01 = A[0], a23 = A[1];
    float4 b01 = B[0], b23 = B[1];
    float4 acc = make_float4(0.f, 0.f, 0.f, 0.f);
#pragma unroll
    for (int h = 0; h < 8; ++h) {  // ternaries fold at compile time
        float sx0 = (h == 0) ? a01.x : (h == 1) ? a01.y : (h == 2) ? a01.z :
                    (h == 3) ? a01.w : (h == 4) ? a23.x : (h == 5) ? a23.y :
                    (h == 6) ? a23.z : a23.w;
        float sx1 = (h == 0) ? b01.x : (h == 1) ? b01.y : (h == 2) ? b01.z :
                    (h == 3) ? b01.w : (h == 4) ? b23.x : (h == 5) ? b23.y :
                    (h == 6) ? b23.z : b23.w;
#pragma unroll
        for (int c = 0; c < 16; ++c) {
            int col = h * 16 + c;
            float4 p = pk1[col];
            float o = fmaxf(p.x * sx0 + p.y * sx1 + p.z, 0.0f);
            float4 w = pk2[col];
            acc.x += o * w.x;
            acc.y += o * w.y;
            acc.z += o * w.z;
            acc.w += o * w.w;
        }
    }
    ((float4*)h2)[n] = acc;
}

// ================= layer 2: per-bucket EDGE-PARALLEL + log_softmax =================
// 1 lane/record: h2[src] 16B gather (L2-resident, 1.6MB), 1 exp, 5 LDS-atomic
// adds into acc[5][132]. Epilogue: 128 threads normalize + bias + log_softmax,
// coalesced float4 out.
__global__ __launch_bounds__(512) void k_att2(
        const unsigned* __restrict__ sbuf, const int* __restrict__ table,
        const float* __restrict__ h2v, const float* __restrict__ att_src2,
        const float* __restrict__ att_dst2, const float* __restrict__ b2,
        float* __restrict__ out, int N, int E, int NBUCK) {
    __shared__ float ad2[128];
    __shared__ float acc[660];   // 5 planes x 132: L, x, y, z, w
    int b = blockIdx.x, t = threadIdx.x;
    int base = b << BSHIFT;
    const float4* h4 = (const float4*)h2v;
    float4 as2 = *(const float4*)att_src2;
    for (int i = t; i < 660; i += 512) acc[i] = 0.f;
    if (t < 128) {
        int n = base + t;
        if (n < N) {
            float4 ad2v = *(const float4*)att_dst2;
            float4 hn = h4[n];
            ad2[t] = hn.x * ad2v.x + hn.y * ad2v.y + hn.z * ad2v.z + hn.w * ad2v.w;
        } else {
            ad2[t] = 0.f;
        }
    }
    __syncthreads();
    int lo = table[b * SLICES];
    int hi = (b + 1 < NBUCK) ? table[(b + 1) * SLICES] : E;
    for (int j = lo + t; j < hi; j += 512) {
        unsigned v = sbuf[j];
        int src = (int)(v & SRCMASK);
        int d = (int)(v >> 17);
        float4 hv = h4[src];
        float e = fmaf(hv.x, as2.x, fmaf(hv.y, as2.y,
                  fmaf(hv.z, as2.z, fmaf(hv.w, as2.w, ad2[d]))));
        float p = __expf(leaky(e));
        atomicAdd(&acc[d], p);
        atomicAdd(&acc[132 + d], p * hv.x);
        atomicAdd(&acc[264 + d], p * hv.y);
        atomicAdd(&acc[396 + d], p * hv.z);
        atomicAdd(&acc[528 + d], p * hv.w);
    }
    __syncthreads();
    if (t < 128) {
        int n = base + t;
        if (n < N) {
            float inv = 1.0f / (acc[t] + kEps);
            float4 v4 = make_float4(acc[132 + t] * inv + b2[0],
                                    acc[264 + t] * inv + b2[1],
                                    acc[396 + t] * inv + b2[2],
                                    acc[528 + t] * inv + b2[3]);
            float mx = fmaxf(fmaxf(v4.x, v4.y), fmaxf(v4.z, v4.w));
            float sum = __expf(v4.x - mx) + __expf(v4.y - mx) +
                        __expf(v4.z - mx) + __expf(v4.w - mx);
            float lse = mx + logf(sum);
            ((float4*)out)[n] = make_float4(v4.x - lse, v4.y - lse,
                                            v4.z - lse, v4.w - lse);
        }
    }
}

extern "C" void kernel_launch(void* const* d_in, const int* in_sizes, int n_in,
                              void* d_out, int out_size, void* d_ws, size_t ws_size,
                              hipStream_t stream) {
    const float* x        = (const float*)d_in[0];
    const int*   ei       = (const int*)d_in[1];
    const float* W1       = (const float*)d_in[2];
    const float* att_src1 = (const float*)d_in[3];
    const float* att_dst1 = (const float*)d_in[4];
    const float* b1       = (const float*)d_in[5];
    const float* W2       = (const float*)d_in[6];
    const float* att_src2 = (const float*)d_in[7];
    const float* att_dst2 = (const float*)d_in[8];
    const float* b2       = (const float*)d_in[9];

    const int N = in_sizes[0] / 2;           // x is [N,2]
    const int E = in_sizes[1] / 2;           // edge_index is [2,E]
    const int NBUCK = (N + BMASK) >> BSHIFT; // 128-node buckets (<= 832)
    const int ntable = NBUCK * SLICES;
    const int nsb = (ntable + 1023) / 1024;  // scan chunks

    // ---- workspace layout (4B elems); ~15.3MB <= R3's proven ~15.7MB ----
    int* table     = (int*)d_ws;                  // ntable (+64 pad)
    int* partial   = table + ntable + 64;         // nsb (pad 1024)
    unsigned* sbuf = (unsigned*)(partial + 1024); // E (lives through att1+att2)
    float* attA    = (float*)(sbuf + E);          // N*8
    float* attB    = attA + (size_t)N * 8;        // N*8
    float* h2      = attB + (size_t)N * 8;        // N*4

    // bucketed partition (by destination), no global atomics, NO SORT
    k_hist1<<<SLICES, 512, 0, stream>>>(ei, table, E, NBUCK);
    k_scan_reduce<<<nsb, 256, 0, stream>>>(table, partial, ntable);
    k_scan_apply<<<nsb, 256, 0, stream>>>(table, partial, ntable, nsb);
    k_bin2<<<SLICES, 512, 0, stream>>>(ei, table, sbuf, E, NBUCK);

    // layer 1: edge-parallel per-bucket attention -> dense MLP fold
    k_att1<<<NBUCK, 512, 0, stream>>>(sbuf, table, x, W1, att_src1, att_dst1,
                                      attA, attB, N, E, NBUCK);
    k_fold<<<(N + 255) / 256, 256, 0, stream>>>(attA, attB, W1, b1, W2, h2, N);

    // layer 2: edge-parallel per-bucket attention + log_softmax
    k_att2<<<NBUCK, 512, 0, stream>>>(sbuf, table, h2, att_src2, att_dst2, b2,
                                      (float*)d_out, N, E, NBUCK);
}

// Round 7
// 152.751 us; speedup vs baseline: 2.7619x; 2.7619x over previous
//
#include <hip/hip_runtime.h>
#include <math.h>

static constexpr float kNegSlope = 0.2f;
static constexpr float kEps = 1e-16f;
static constexpr int SLICES = 512;   // R6: 256->512 — hist/bin2 were 1 block/CU
                                     // (25% occ, latency-bound); 512 gives 2/CU.
static constexpr int BSHIFT = 7;     // 128 nodes per bucket
static constexpr int BMASK = 127;
static constexpr unsigned SRCMASK = 0x1FFFFu;  // 17 bits (N < 131072)
static constexpr int CAP = 2816;     // LDS bucket capacity (mean 2048, +17 sigma)

__device__ __forceinline__ float leaky(float v) {
    return v > 0.0f ? v : kNegSlope * v;
}

// ================= atomic-free bucketed partition (PROVEN form) =================
// bucket = dst >> 7 (128 nodes). Per-slice private LDS histograms ->
// scan of table[bucket][slice] -> deterministic scatter with LDS cursors.
// Record: src | (d&127)<<17 (24 bits, 4B). LEDGER: global-atomic node-level
// scatter = 107MB write amplification, 134us (R4). Edge-parallel LDS-float-
// atomic accumulation = same-address serialization, 261us (R5). Do not retry.

__global__ __launch_bounds__(512) void k_hist1(const int* __restrict__ ei,
                                               int* __restrict__ table,
                                               int* __restrict__ rowptr,
                                               int E, int N, int NBUCK) {
    __shared__ int hist[832];
    int b = blockIdx.x, t = threadIdx.x;
    if (b == 0 && t == 0) rowptr[N] = E;  // sentinel
    for (int i = t; i < NBUCK; i += 512) hist[i] = 0;
    __syncthreads();
    int S = (((E + SLICES - 1) / SLICES) + 3) & ~3;  // slice size, multiple of 4
    int lo = b * S, hi = min(lo + S, E);
    for (int i = lo + t * 4; i < hi; i += 512 * 4) {
        int4 dv = *(const int4*)(ei + E + i);
        atomicAdd(&hist[dv.x >> BSHIFT], 1);
        atomicAdd(&hist[dv.y >> BSHIFT], 1);
        atomicAdd(&hist[dv.z >> BSHIFT], 1);
        atomicAdd(&hist[dv.w >> BSHIFT], 1);
    }
    __syncthreads();
    for (int i = t; i < NBUCK; i += 512) table[i * SLICES + b] = hist[i];
}

// Scan pass 1: block b sums its 1024-int chunk -> partial[b].
__global__ __launch_bounds__(256) void k_scan_reduce(const int* __restrict__ src,
                                                     int* __restrict__ partial, int n) {
    __shared__ int wsum[4];
    int b = blockIdx.x, t = threadIdx.x;
    int base = b * 1024 + t * 4;
    int s = 0;
#pragma unroll
    for (int k = 0; k < 4; ++k) {
        int idx = base + k;
        s += (idx < n) ? src[idx] : 0;
    }
#pragma unroll
    for (int off = 1; off < 64; off <<= 1) s += __shfl_xor(s, off);
    if ((t & 63) == 0) wsum[t >> 6] = s;
    __syncthreads();
    if (t == 0) partial[b] = wsum[0] + wsum[1] + wsum[2] + wsum[3];
}

// Scan pass 2: block b computes its chunk base by reducing partial[i<b],
// then wave-scans its 1024-int chunk in place (exclusive).
__global__ __launch_bounds__(256) void k_scan_apply(int* __restrict__ data,
                                                    const int* __restrict__ partial,
                                                    int n, int nsb) {
    __shared__ int sm[8];
    __shared__ int baseSh;
    int b = blockIdx.x, t = threadIdx.x;
    int acc = 0;
    for (int i = t; i < b; i += 256) acc += partial[i];
#pragma unroll
    for (int off = 1; off < 64; off <<= 1) acc += __shfl_xor(acc, off);
    if ((t & 63) == 0) sm[t >> 6] = acc;
    __syncthreads();
    if (t == 0) baseSh = sm[0] + sm[1] + sm[2] + sm[3];
    __syncthreads();
    int chunkBase = baseSh;
    __syncthreads();  // sm reused below
    int base = b * 1024 + t * 4;
    int v[4];
#pragma unroll
    for (int k = 0; k < 4; ++k) {
        int idx = base + k;
        v[k] = (idx < n) ? data[idx] : 0;
    }
    int sum4 = v[0] + v[1] + v[2] + v[3];
    int s = sum4;
#pragma unroll
    for (int off = 1; off < 64; off <<= 1) {
        int u = __shfl_up(s, off);
        if ((t & 63) >= off) s += u;
    }
    if ((t & 63) == 63) sm[t >> 6] = s;
    __syncthreads();
    int woff = 0;
    int w = t >> 6;
    for (int ww = 0; ww < w; ++ww) woff += sm[ww];
    int ex = chunkBase + woff + (s - sum4);
#pragma unroll
    for (int k = 0; k < 4; ++k) {
        int idx = base + k;
        if (idx < n) data[idx] = ex;
        ex += v[k];
    }
}

__global__ __launch_bounds__(512) void k_bin2(const int* __restrict__ ei,
                                              const int* __restrict__ table,
                                              unsigned* __restrict__ sbuf, int E, int NBUCK) {
    __shared__ int cur[832];
    int b = blockIdx.x, t = threadIdx.x;
    for (int i = t; i < NBUCK; i += 512) cur[i] = table[i * SLICES + b];
    __syncthreads();
    int S = (((E + SLICES - 1) / SLICES) + 3) & ~3;
    int lo = b * S, hi = min(lo + S, E);
    for (int i = lo + t * 4; i < hi; i += 512 * 4) {
        int4 sv = *(const int4*)(ei + i);
        int4 dv = *(const int4*)(ei + E + i);
        int pos;
        pos = atomicAdd(&cur[dv.x >> BSHIFT], 1);
        sbuf[pos] = (unsigned)sv.x | ((unsigned)(dv.x & BMASK) << 17);
        pos = atomicAdd(&cur[dv.y >> BSHIFT], 1);
        sbuf[pos] = (unsigned)sv.y | ((unsigned)(dv.y & BMASK) << 17);
        pos = atomicAdd(&cur[dv.z >> BSHIFT], 1);
        sbuf[pos] = (unsigned)sv.z | ((unsigned)(dv.z & BMASK) << 17);
        pos = atomicAdd(&cur[dv.w >> BSHIFT], 1);
        sbuf[pos] = (unsigned)sv.w | ((unsigned)(dv.w & BMASK) << 17);
    }
}

// ================= per-bucket counting sort -> CSR =================
// One 512-thread block per 128-node bucket: stage records into LDS, hist,
// two-wave shfl scan -> rowptr, LDS->LDS counting sort, COALESCED ssrc
// writeback. No gather work here — R18 showed fusing the gather into this
// block serializes it behind the sort phases. Keep blocks short.
__global__ __launch_bounds__(512) void k_sort(
        const unsigned* __restrict__ sbuf, const int* __restrict__ table,
        int* __restrict__ rowptr, int* __restrict__ ssrc,
        int N, int E, int NBUCK) {
    __shared__ int hist[128];
    __shared__ int sc[128];
    __shared__ int cur[128];
    __shared__ unsigned raws[CAP];
    __shared__ int sls[CAP];
    int b = blockIdx.x;
    int t = threadIdx.x;
    int lo = table[b * SLICES];
    int hi = (b + 1 < NBUCK) ? table[(b + 1) * SLICES] : E;
    int cnt = hi - lo;
    bool inLds = (cnt <= CAP);

    if (t < 128) hist[t] = 0;
    __syncthreads();

    if (inLds) {
        for (int i = t; i < cnt; i += 512) {
            unsigned v = sbuf[lo + i];
            raws[i] = v;
            atomicAdd(&hist[v >> 17], 1);
        }
    } else {
        for (int i = lo + t; i < hi; i += 512) atomicAdd(&hist[sbuf[i] >> 17], 1);
    }
    __syncthreads();

    if (t < 128) {  // two-wave shfl inclusive scan of 128 bins
        int lane = t & 63;
        int own = hist[t];
        int v = own;
#pragma unroll
        for (int off = 1; off < 64; off <<= 1) {
            int u = __shfl_up(v, off);
            if (lane >= off) v += u;
        }
        sc[t] = v;
    }
    __syncthreads();
    if (t < 128) {
        int ex = sc[t] - hist[t] + (t >= 64 ? sc[63] : 0);
        cur[t] = ex;
        int node = (b << BSHIFT) + t;
        if (node < N) rowptr[node] = lo + ex;
    }
    __syncthreads();

    if (inLds) {
        for (int i = t; i < cnt; i += 512) {
            unsigned v = raws[i];
            int pos = atomicAdd(&cur[v >> 17], 1);
            sls[pos] = (int)(v & SRCMASK);
        }
        __syncthreads();
        for (int i = t; i < cnt; i += 512) ssrc[lo + i] = sls[i];  // coalesced
    } else {  // overflow fallback (statistically never: mean 2048, CAP 2816)
        for (int i = lo + t; i < hi; i += 512) {
            unsigned v = sbuf[i];
            int pos = atomicAdd(&cur[v >> 17], 1);
            ssrc[lo + pos] = (int)(v & SRCMASK);
        }
    }
}

// ================= layer 1 attention accumulate (node-parallel) =================
// 8 lanes/node, unroll-2 edge loop, direct x gather (R0: gather == stream;
// R1: wider MLP batching regresses; R3: 16-lane split is a wash — lanes x
// instr product is invariant). Ends at the softmax reduce; emits normalized
// (sX0,sX1) per (node,head); k_fold does the dense W1->relu->W2 (R2: -20us).
// Straight-line softmax (no max): inputs N(0,1)-scale, |e|<~8 — validated
// R8-R18.
__global__ __launch_bounds__(256) void k_gather1(
        const int* __restrict__ rowptr, const int* __restrict__ ssrc,
        const float* __restrict__ x,
        const float* __restrict__ W1, const float* __restrict__ att_src1,
        const float* __restrict__ att_dst1,
        float* __restrict__ attA, float* __restrict__ attB, int N) {
    __shared__ float pbuf[32];  // Ps d0 | Ps d1 | Pd d0 | Pd d1 (8 heads each)
    int t = threadIdx.x;
    if (t < 32) {  // rank-2 projections
        int which = t >> 4;   // 0=src, 1=dst
        int hd = t & 15;
        int h = hd >> 1, d = hd & 1;
        const float* att = which ? att_dst1 : att_src1;
        float s = 0.0f;
#pragma unroll
        for (int c = 0; c < 16; ++c) s += W1[d * 128 + h * 16 + c] * att[h * 16 + c];
        pbuf[which * 16 + d * 8 + h] = s;
    }
    __syncthreads();

    int idx = blockIdx.x * blockDim.x + t;
    int n = idx >> 3, q = idx & 7;
    if (n >= N) return;
    const float2* x2 = (const float2*)x;
    int start = rowptr[n], end = rowptr[n + 1];
    float2 xn = x2[n];
    float Ps0[8], Ps1[8], adv[8], l[8], s0[8], s1[8];
#pragma unroll
    for (int h = 0; h < 8; ++h) {
        Ps0[h] = pbuf[h];
        Ps1[h] = pbuf[8 + h];
        adv[h] = xn.x * pbuf[16 + h] + xn.y * pbuf[24 + h];
        l[h] = 0.f; s0[h] = 0.f; s1[h] = 0.f;
    }
    int j = start + q;
    for (; j + 8 < end; j += 16) {  // unroll-2: two independent gathers
        int sa = ssrc[j];
        int sb = ssrc[j + 8];
        float2 xa = x2[sa];
        float2 xb = x2[sb];
#pragma unroll
        for (int h = 0; h < 8; ++h) {
            float pa = __expf(leaky(fmaf(xa.x, Ps0[h], fmaf(xa.y, Ps1[h], adv[h]))));
            float pb = __expf(leaky(fmaf(xb.x, Ps0[h], fmaf(xb.y, Ps1[h], adv[h]))));
            l[h] += pa + pb;
            s0[h] = fmaf(pa, xa.x, fmaf(pb, xb.x, s0[h]));
            s1[h] = fmaf(pa, xa.y, fmaf(pb, xb.y, s1[h]));
        }
    }
    if (j < end) {  // at most one tail edge per lane
        int sa = ssrc[j];
        float2 xa = x2[sa];
#pragma unroll
        for (int h = 0; h < 8; ++h) {
            float pa = __expf(leaky(fmaf(xa.x, Ps0[h], fmaf(xa.y, Ps1[h], adv[h]))));
            l[h] += pa;
            s0[h] = fmaf(pa, xa.x, s0[h]);
            s1[h] = fmaf(pa, xa.y, s1[h]);
        }
    }
#pragma unroll
    for (int off = 1; off < 8; off <<= 1) {
#pragma unroll
        for (int h = 0; h < 8; ++h) {
            l[h] += __shfl_xor(l[h], off);
            s0[h] += __shfl_xor(s0[h], off);
            s1[h] += __shfl_xor(s1[h], off);
        }
    }
    // lane q emits head q's normalized feature pair (planar, coalesced)
    float inv = 1.0f / (l[q] + kEps);
    attA[n * 8 + q] = s0[q] * inv;
    attB[n * 8 + q] = s1[q] * inv;
}

// ================= dense per-node MLP: W1 -> relu -> W2 =================
// 1 thread/node. Weights packed into two float4 LDS tables (uniform-address
// broadcast reads, conflict-free).
__global__ __launch_bounds__(256) void k_fold(
        const float* __restrict__ attA, const float* __restrict__ attB,
        const float* __restrict__ W1, const float* __restrict__ b1,
        const float* __restrict__ W2, float* __restrict__ h2, int N) {
    __shared__ float4 pk1[128];  // (W1a, W1b, b1, 0) per col
    __shared__ float4 pk2[128];  // W2 row per col
    int t = threadIdx.x;
    if (t < 128) {
        pk1[t] = make_float4(W1[t], W1[128 + t], b1[t], 0.f);
        pk2[t] = ((const float4*)W2)[t];
    }
    __syncthreads();
    int n = blockIdx.x * 256 + t;
    if (n >= N) return;
    const float4* A = (const float4*)(attA + n * 8);
    const float4* B = (const float4*)(attB + n * 8);
    float4 a01 = A[0], a23 = A[1];
    float4 b01 = B[0], b23 = B[1];
    float4 acc = make_float4(0.f, 0.f, 0.f, 0.f);
#pragma unroll
    for (int h = 0; h < 8; ++h) {  // ternaries fold at compile time
        float sx0 = (h == 0) ? a01.x : (h == 1) ? a01.y : (h == 2) ? a01.z :
                    (h == 3) ? a01.w : (h == 4) ? a23.x : (h == 5) ? a23.y :
                    (h == 6) ? a23.z : a23.w;
        float sx1 = (h == 0) ? b01.x : (h == 1) ? b01.y : (h == 2) ? b01.z :
                    (h == 3) ? b01.w : (h == 4) ? b23.x : (h == 5) ? b23.y :
                    (h == 6) ? b23.z : b23.w;
#pragma unroll
        for (int c = 0; c < 16; ++c) {
            int col = h * 16 + c;
            float4 p = pk1[col];
            float o = fmaxf(p.x * sx0 + p.y * sx1 + p.z, 0.0f);
            float4 w = pk2[col];
            acc.x += o * w.x;
            acc.y += o * w.y;
            acc.z += o * w.z;
            acc.w += o * w.w;
        }
    }
    ((float4*)h2)[n] = acc;
}

// ================= layer 2 gather + log_softmax =================
// 8 lanes/node; unroll-2 keeps two independent ssrc->h2 chains in flight.
__global__ __launch_bounds__(256) void k_gather2_out(
        const int* __restrict__ rowptr, const int* __restrict__ ssrc,
        const float* __restrict__ h2, const float* __restrict__ att_src2,
        const float* __restrict__ att_dst2, const float* __restrict__ b2,
        float* __restrict__ out, int N) {
    int idx = blockIdx.x * blockDim.x + threadIdx.x;
    int n = idx >> 3, q = idx & 7;
    if (n >= N) return;
    int start = rowptr[n], end = rowptr[n + 1];
    float4 as2 = *(const float4*)att_src2;
    float4 ad2v = *(const float4*)att_dst2;
    const float4* h4 = (const float4*)h2;
    float4 hn = h4[n];
    float ad = hn.x * ad2v.x + hn.y * ad2v.y + hn.z * ad2v.z + hn.w * ad2v.w;
    float l = 0.0f;
    float4 acc = make_float4(0.f, 0.f, 0.f, 0.f);
    int j = start + q;
    for (; j + 8 < end; j += 16) {  // two independent gathers in flight
        int s0 = ssrc[j];
        int s1 = ssrc[j + 8];
        float4 ha = h4[s0];
        float4 hb = h4[s1];
        float e0 = ha.x * as2.x + ha.y * as2.y + ha.z * as2.z + ha.w * as2.w + ad;
        float e1 = hb.x * as2.x + hb.y * as2.y + hb.z * as2.z + hb.w * as2.w + ad;
        float p0 = __expf(leaky(e0));
        float p1 = __expf(leaky(e1));
        l += p0 + p1;
        acc.x += p0 * ha.x + p1 * hb.x;
        acc.y += p0 * ha.y + p1 * hb.y;
        acc.z += p0 * ha.z + p1 * hb.z;
        acc.w += p0 * ha.w + p1 * hb.w;
    }
    if (j < end) {  // at most one tail edge per lane
        int s0 = ssrc[j];
        float4 ha = h4[s0];
        float e0 = ha.x * as2.x + ha.y * as2.y + ha.z * as2.z + ha.w * as2.w + ad;
        float p0 = __expf(leaky(e0));
        l += p0;
        acc.x += p0 * ha.x;
        acc.y += p0 * ha.y;
        acc.z += p0 * ha.z;
        acc.w += p0 * ha.w;
    }
#pragma unroll
    for (int off = 1; off < 8; off <<= 1) {
        l += __shfl_xor(l, off);
        acc.x += __shfl_xor(acc.x, off);
        acc.y += __shfl_xor(acc.y, off);
        acc.z += __shfl_xor(acc.z, off);
        acc.w += __shfl_xor(acc.w, off);
    }
    if (q == 0) {
        float inv = 1.0f / (l + kEps);
        float4 v = make_float4(acc.x * inv + b2[0], acc.y * inv + b2[1],
                               acc.z * inv + b2[2], acc.w * inv + b2[3]);
        float mx = fmaxf(fmaxf(v.x, v.y), fmaxf(v.z, v.w));
        float sum = __expf(v.x - mx) + __expf(v.y - mx) + __expf(v.z - mx) + __expf(v.w - mx);
        float lse = mx + logf(sum);
        ((float4*)out)[n] = make_float4(v.x - lse, v.y - lse, v.z - lse, v.w - lse);
    }
}

extern "C" void kernel_launch(void* const* d_in, const int* in_sizes, int n_in,
                              void* d_out, int out_size, void* d_ws, size_t ws_size,
                              hipStream_t stream) {
    const float* x        = (const float*)d_in[0];
    const int*   ei       = (const int*)d_in[1];
    const float* W1       = (const float*)d_in[2];
    const float* att_src1 = (const float*)d_in[3];
    const float* att_dst1 = (const float*)d_in[4];
    const float* b1       = (const float*)d_in[5];
    const float* W2       = (const float*)d_in[6];
    const float* att_src2 = (const float*)d_in[7];
    const float* att_dst2 = (const float*)d_in[8];
    const float* b2       = (const float*)d_in[9];

    const int N = in_sizes[0] / 2;           // x is [N,2]
    const int E = in_sizes[1] / 2;           // edge_index is [2,E]
    const int NBUCK = (N + BMASK) >> BSHIFT; // 128-node buckets (<= 832)
    const int ntable = NBUCK * SLICES;
    const int nsb = (ntable + 1023) / 1024;  // scan chunks

    // ---- workspace layout (4B elems); ~16.4MB (ws is >=256MB per fills) ----
    int* table     = (int*)d_ws;                  // ntable (+64 pad)
    int* partial   = table + ntable + 64;         // nsb (pad 1024)
    int* rowptr    = partial + 1024;              // N+1 -> pad N+4
    int* ssrc      = rowptr + ((N + 4) & ~3);     // E
    unsigned* sbuf = (unsigned*)(ssrc + E);       // E (dead after k_sort)
    float* attA    = (float*)sbuf;                // N*8 floats (overlay)
    float* attB    = attA + (size_t)N * 8;        // N*8 floats
    size_t post    = (size_t)E > (size_t)N * 16 ? (size_t)E : (size_t)N * 16;
    float* h2      = (float*)(sbuf + post);       // N*4 floats

    // bucketed partition (by destination), no global atomics
    k_hist1<<<SLICES, 512, 0, stream>>>(ei, table, rowptr, E, N, NBUCK);
    k_scan_reduce<<<nsb, 256, 0, stream>>>(table, partial, ntable);
    k_scan_apply<<<nsb, 256, 0, stream>>>(table, partial, ntable, nsb);
    k_bin2<<<SLICES, 512, 0, stream>>>(ei, table, sbuf, E, NBUCK);

    // per-bucket counting sort -> CSR
    k_sort<<<NBUCK, 512, 0, stream>>>(sbuf, table, rowptr, ssrc, N, E, NBUCK);

    // layer 1: attention accumulate (lean) -> dense MLP fold
    k_gather1<<<(N * 8 + 255) / 256, 256, 0, stream>>>(rowptr, ssrc, x,
                                                       W1, att_src1, att_dst1,
                                                       attA, attB, N);
    k_fold<<<(N + 255) / 256, 256, 0, stream>>>(attA, attB, W1, b1, W2, h2, N);

    // layer 2 gather + log_softmax
    k_gather2_out<<<(N * 8 + 255) / 256, 256, 0, stream>>>(rowptr, ssrc, h2,
                                                           att_src2, att_dst2, b2,
                                                           (float*)d_out, N);
}

// Round 8
// 151.466 us; speedup vs baseline: 2.7853x; 1.0085x over previous
//
#include <hip/hip_runtime.h>
#include <math.h>

static constexpr float kNegSlope = 0.2f;
static constexpr float kEps = 1e-16f;
static constexpr float kLog2e = 1.44269504088896340736f;
static constexpr int SLICES = 256;   // R6: 512 was null -> reverted to proven 256
static constexpr int BSHIFT = 7;     // 128 nodes per bucket
static constexpr int BMASK = 127;
static constexpr unsigned SRCMASK = 0x1FFFFu;  // 17 bits (N < 131072)
static constexpr int CAP = 2816;     // LDS bucket capacity (mean 2048, +17 sigma)

// leaky(v) = fmaxf(v, 0.2v): exact identity (0.2>0), 2 VALU ops vs 3 for cmp/sel.
__device__ __forceinline__ float leakymax(float v) {
    return fmaxf(v, kNegSlope * v);
}

// Raw 2^x (v_exp_f32). Projections are pre-scaled by log2(e), so
// 2^leaky(z*log2e) == e^leaky(z) exactly (leaky commutes with c>0 scaling).
__device__ __forceinline__ float fexp2(float v) {
#if __has_builtin(__builtin_amdgcn_exp2f)
    return __builtin_amdgcn_exp2f(v);
#else
    return exp2f(v);
#endif
}

// ================= atomic-free bucketed partition (PROVEN form) =================
// bucket = dst >> 7 (128 nodes). Per-slice private LDS histograms ->
// scan of table[bucket][slice] -> deterministic scatter with LDS cursors.
// Record: src | (d&127)<<17 (24 bits, 4B). LEDGER: global-atomic node-level
// scatter = 107MB write amplification, 134us (R4). Edge-parallel LDS-float-
// atomic accumulation = same-address serialization, 261us (R5). SLICES=512
// occupancy bump = null (R6). Do not retry.

__global__ __launch_bounds__(512) void k_hist1(const int* __restrict__ ei,
                                               int* __restrict__ table,
                                               int* __restrict__ rowptr,
                                               int E, int N, int NBUCK) {
    __shared__ int hist[832];
    int b = blockIdx.x, t = threadIdx.x;
    if (b == 0 && t == 0) rowptr[N] = E;  // sentinel
    for (int i = t; i < NBUCK; i += 512) hist[i] = 0;
    __syncthreads();
    int S = (((E + SLICES - 1) / SLICES) + 3) & ~3;  // slice size, multiple of 4
    int lo = b * S, hi = min(lo + S, E);
    for (int i = lo + t * 4; i < hi; i += 512 * 4) {
        int4 dv = *(const int4*)(ei + E + i);
        atomicAdd(&hist[dv.x >> BSHIFT], 1);
        atomicAdd(&hist[dv.y >> BSHIFT], 1);
        atomicAdd(&hist[dv.z >> BSHIFT], 1);
        atomicAdd(&hist[dv.w >> BSHIFT], 1);
    }
    __syncthreads();
    for (int i = t; i < NBUCK; i += 512) table[i * SLICES + b] = hist[i];
}

// Scan pass 1: block b sums its 1024-int chunk -> partial[b].
__global__ __launch_bounds__(256) void k_scan_reduce(const int* __restrict__ src,
                                                     int* __restrict__ partial, int n) {
    __shared__ int wsum[4];
    int b = blockIdx.x, t = threadIdx.x;
    int base = b * 1024 + t * 4;
    int s = 0;
#pragma unroll
    for (int k = 0; k < 4; ++k) {
        int idx = base + k;
        s += (idx < n) ? src[idx] : 0;
    }
#pragma unroll
    for (int off = 1; off < 64; off <<= 1) s += __shfl_xor(s, off);
    if ((t & 63) == 0) wsum[t >> 6] = s;
    __syncthreads();
    if (t == 0) partial[b] = wsum[0] + wsum[1] + wsum[2] + wsum[3];
}

// Scan pass 2: block b computes its chunk base by reducing partial[i<b],
// then wave-scans its 1024-int chunk in place (exclusive).
__global__ __launch_bounds__(256) void k_scan_apply(int* __restrict__ data,
                                                    const int* __restrict__ partial,
                                                    int n, int nsb) {
    __shared__ int sm[8];
    __shared__ int baseSh;
    int b = blockIdx.x, t = threadIdx.x;
    int acc = 0;
    for (int i = t; i < b; i += 256) acc += partial[i];
#pragma unroll
    for (int off = 1; off < 64; off <<= 1) acc += __shfl_xor(acc, off);
    if ((t & 63) == 0) sm[t >> 6] = acc;
    __syncthreads();
    if (t == 0) baseSh = sm[0] + sm[1] + sm[2] + sm[3];
    __syncthreads();
    int chunkBase = baseSh;
    __syncthreads();  // sm reused below
    int base = b * 1024 + t * 4;
    int v[4];
#pragma unroll
    for (int k = 0; k < 4; ++k) {
        int idx = base + k;
        v[k] = (idx < n) ? data[idx] : 0;
    }
    int sum4 = v[0] + v[1] + v[2] + v[3];
    int s = sum4;
#pragma unroll
    for (int off = 1; off < 64; off <<= 1) {
        int u = __shfl_up(s, off);
        if ((t & 63) >= off) s += u;
    }
    if ((t & 63) == 63) sm[t >> 6] = s;
    __syncthreads();
    int woff = 0;
    int w = t >> 6;
    for (int ww = 0; ww < w; ++ww) woff += sm[ww];
    int ex = chunkBase + woff + (s - sum4);
#pragma unroll
    for (int k = 0; k < 4; ++k) {
        int idx = base + k;
        if (idx < n) data[idx] = ex;
        ex += v[k];
    }
}

__global__ __launch_bounds__(512) void k_bin2(const int* __restrict__ ei,
                                              const int* __restrict__ table,
                                              unsigned* __restrict__ sbuf, int E, int NBUCK) {
    __shared__ int cur[832];
    int b = blockIdx.x, t = threadIdx.x;
    for (int i = t; i < NBUCK; i += 512) cur[i] = table[i * SLICES + b];
    __syncthreads();
    int S = (((E + SLICES - 1) / SLICES) + 3) & ~3;
    int lo = b * S, hi = min(lo + S, E);
    for (int i = lo + t * 4; i < hi; i += 512 * 4) {
        int4 sv = *(const int4*)(ei + i);
        int4 dv = *(const int4*)(ei + E + i);
        int pos;
        pos = atomicAdd(&cur[dv.x >> BSHIFT], 1);
        sbuf[pos] = (unsigned)sv.x | ((unsigned)(dv.x & BMASK) << 17);
        pos = atomicAdd(&cur[dv.y >> BSHIFT], 1);
        sbuf[pos] = (unsigned)sv.y | ((unsigned)(dv.y & BMASK) << 17);
        pos = atomicAdd(&cur[dv.z >> BSHIFT], 1);
        sbuf[pos] = (unsigned)sv.z | ((unsigned)(dv.z & BMASK) << 17);
        pos = atomicAdd(&cur[dv.w >> BSHIFT], 1);
        sbuf[pos] = (unsigned)sv.w | ((unsigned)(dv.w & BMASK) << 17);
    }
}

// ================= per-bucket counting sort -> CSR =================
// One 512-thread block per 128-node bucket: stage records into LDS, hist,
// two-wave shfl scan -> rowptr, LDS->LDS counting sort, COALESCED ssrc
// writeback. No gather work here — R18 showed fusing the gather into this
// block serializes it behind the sort phases. Keep blocks short.
__global__ __launch_bounds__(512) void k_sort(
        const unsigned* __restrict__ sbuf, const int* __restrict__ table,
        int* __restrict__ rowptr, int* __restrict__ ssrc,
        int N, int E, int NBUCK) {
    __shared__ int hist[128];
    __shared__ int sc[128];
    __shared__ int cur[128];
    __shared__ unsigned raws[CAP];
    __shared__ int sls[CAP];
    int b = blockIdx.x;
    int t = threadIdx.x;
    int lo = table[b * SLICES];
    int hi = (b + 1 < NBUCK) ? table[(b + 1) * SLICES] : E;
    int cnt = hi - lo;
    bool inLds = (cnt <= CAP);

    if (t < 128) hist[t] = 0;
    __syncthreads();

    if (inLds) {
        for (int i = t; i < cnt; i += 512) {
            unsigned v = sbuf[lo + i];
            raws[i] = v;
            atomicAdd(&hist[v >> 17], 1);
        }
    } else {
        for (int i = lo + t; i < hi; i += 512) atomicAdd(&hist[sbuf[i] >> 17], 1);
    }
    __syncthreads();

    if (t < 128) {  // two-wave shfl inclusive scan of 128 bins
        int lane = t & 63;
        int own = hist[t];
        int v = own;
#pragma unroll
        for (int off = 1; off < 64; off <<= 1) {
            int u = __shfl_up(v, off);
            if (lane >= off) v += u;
        }
        sc[t] = v;
    }
    __syncthreads();
    if (t < 128) {
        int ex = sc[t] - hist[t] + (t >= 64 ? sc[63] : 0);
        cur[t] = ex;
        int node = (b << BSHIFT) + t;
        if (node < N) rowptr[node] = lo + ex;
    }
    __syncthreads();

    if (inLds) {
        for (int i = t; i < cnt; i += 512) {
            unsigned v = raws[i];
            int pos = atomicAdd(&cur[v >> 17], 1);
            sls[pos] = (int)(v & SRCMASK);
        }
        __syncthreads();
        for (int i = t; i < cnt; i += 512) ssrc[lo + i] = sls[i];  // coalesced
    } else {  // overflow fallback (statistically never: mean 2048, CAP 2816)
        for (int i = lo + t; i < hi; i += 512) {
            unsigned v = sbuf[i];
            int pos = atomicAdd(&cur[v >> 17], 1);
            ssrc[lo + pos] = (int)(v & SRCMASK);
        }
    }
}

// ================= layer 1 attention accumulate (node-parallel) =================
// 8 lanes/node, unroll-2 edge loop, direct x gather (R0: gather == stream;
// R1: wider MLP batching regresses; R3: 16-lane split is a wash). Ends at the
// softmax reduce; emits normalized (sX0,sX1) per (node,head); k_fold does the
// dense W1->relu->W2 (R2: -20us). R7: projections pre-scaled by log2(e) and
// leaky as fmax — per (edge,head) score path 7->5 VALU ops, exp is a bare
// v_exp_f32. Straight-line softmax (no max): inputs N(0,1)-scale, |e|<~8.
__global__ __launch_bounds__(256) void k_gather1(
        const int* __restrict__ rowptr, const int* __restrict__ ssrc,
        const float* __restrict__ x,
        const float* __restrict__ W1, const float* __restrict__ att_src1,
        const float* __restrict__ att_dst1,
        float* __restrict__ attA, float* __restrict__ attB, int N) {
    __shared__ float pbuf[32];  // Ps d0 | Ps d1 | Pd d0 | Pd d1 (8 heads each)
    int t = threadIdx.x;
    if (t < 32) {  // rank-2 projections, PRE-SCALED by log2(e)
        int which = t >> 4;   // 0=src, 1=dst
        int hd = t & 15;
        int h = hd >> 1, d = hd & 1;
        const float* att = which ? att_dst1 : att_src1;
        float s = 0.0f;
#pragma unroll
        for (int c = 0; c < 16; ++c) s += W1[d * 128 + h * 16 + c] * att[h * 16 + c];
        pbuf[which * 16 + d * 8 + h] = s * kLog2e;
    }
    __syncthreads();

    int idx = blockIdx.x * blockDim.x + t;
    int n = idx >> 3, q = idx & 7;
    if (n >= N) return;
    const float2* x2 = (const float2*)x;
    int start = rowptr[n], end = rowptr[n + 1];
    float2 xn = x2[n];
    float Ps0[8], Ps1[8], adv[8], l[8], s0[8], s1[8];
#pragma unroll
    for (int h = 0; h < 8; ++h) {
        Ps0[h] = pbuf[h];
        Ps1[h] = pbuf[8 + h];
        adv[h] = xn.x * pbuf[16 + h] + xn.y * pbuf[24 + h];
        l[h] = 0.f; s0[h] = 0.f; s1[h] = 0.f;
    }
    int j = start + q;
    for (; j + 8 < end; j += 16) {  // unroll-2: two independent gathers
        int sa = ssrc[j];
        int sb = ssrc[j + 8];
        float2 xa = x2[sa];
        float2 xb = x2[sb];
#pragma unroll
        for (int h = 0; h < 8; ++h) {
            float pa = fexp2(leakymax(fmaf(xa.x, Ps0[h], fmaf(xa.y, Ps1[h], adv[h]))));
            float pb = fexp2(leakymax(fmaf(xb.x, Ps0[h], fmaf(xb.y, Ps1[h], adv[h]))));
            l[h] += pa + pb;
            s0[h] = fmaf(pa, xa.x, fmaf(pb, xb.x, s0[h]));
            s1[h] = fmaf(pa, xa.y, fmaf(pb, xb.y, s1[h]));
        }
    }
    if (j < end) {  // at most one tail edge per lane
        int sa = ssrc[j];
        float2 xa = x2[sa];
#pragma unroll
        for (int h = 0; h < 8; ++h) {
            float pa = fexp2(leakymax(fmaf(xa.x, Ps0[h], fmaf(xa.y, Ps1[h], adv[h]))));
            l[h] += pa;
            s0[h] = fmaf(pa, xa.x, s0[h]);
            s1[h] = fmaf(pa, xa.y, s1[h]);
        }
    }
#pragma unroll
    for (int off = 1; off < 8; off <<= 1) {
#pragma unroll
        for (int h = 0; h < 8; ++h) {
            l[h] += __shfl_xor(l[h], off);
            s0[h] += __shfl_xor(s0[h], off);
            s1[h] += __shfl_xor(s1[h], off);
        }
    }
    // lane q emits head q's normalized feature pair (planar, coalesced)
    float inv = 1.0f / (l[q] + kEps);
    attA[n * 8 + q] = s0[q] * inv;
    attB[n * 8 + q] = s1[q] * inv;
}

// ================= dense per-node MLP: W1 -> relu -> W2 =================
// 1 thread/node. Weights packed into two float4 LDS tables (uniform-address
// broadcast reads, conflict-free).
__global__ __launch_bounds__(256) void k_fold(
        const float* __restrict__ attA, const float* __restrict__ attB,
        const float* __restrict__ W1, const float* __restrict__ b1,
        const float* __restrict__ W2, float* __restrict__ h2, int N) {
    __shared__ float4 pk1[128];  // (W1a, W1b, b1, 0) per col
    __shared__ float4 pk2[128];  // W2 row per col
    int t = threadIdx.x;
    if (t < 128) {
        pk1[t] = make_float4(W1[t], W1[128 + t], b1[t], 0.f);
        pk2[t] = ((const float4*)W2)[t];
    }
    __syncthreads();
    int n = blockIdx.x * 256 + t;
    if (n >= N) return;
    const float4* A = (const float4*)(attA + n * 8);
    const float4* B = (const float4*)(attB + n * 8);
    float4 a01 = A[0], a23 = A[1];
    float4 b01 = B[0], b23 = B[1];
    float4 acc = make_float4(0.f, 0.f, 0.f, 0.f);
#pragma unroll
    for (int h = 0; h < 8; ++h) {  // ternaries fold at compile time
        float sx0 = (h == 0) ? a01.x : (h == 1) ? a01.y : (h == 2) ? a01.z :
                    (h == 3) ? a01.w : (h == 4) ? a23.x : (h == 5) ? a23.y :
                    (h == 6) ? a23.z : a23.w;
        float sx1 = (h == 0) ? b01.x : (h == 1) ? b01.y : (h == 2) ? b01.z :
                    (h == 3) ? b01.w : (h == 4) ? b23.x : (h == 5) ? b23.y :
                    (h == 6) ? b23.z : b23.w;
#pragma unroll
        for (int c = 0; c < 16; ++c) {
            int col = h * 16 + c;
            float4 p = pk1[col];
            float o = fmaxf(p.x * sx0 + p.y * sx1 + p.z, 0.0f);
            float4 w = pk2[col];
            acc.x += o * w.x;
            acc.y += o * w.y;
            acc.z += o * w.z;
            acc.w += o * w.w;
        }
    }
    ((float4*)h2)[n] = acc;
}

// ================= layer 2 gather + log_softmax =================
// 8 lanes/node; unroll-2 keeps two independent ssrc->h2 chains in flight.
// R7: as2/ad pre-scaled by log2(e), leaky as fmax, bare v_exp_f32.
__global__ __launch_bounds__(256) void k_gather2_out(
        const int* __restrict__ rowptr, const int* __restrict__ ssrc,
        const float* __restrict__ h2, const float* __restrict__ att_src2,
        const float* __restrict__ att_dst2, const float* __restrict__ b2,
        float* __restrict__ out, int N) {
    int idx = blockIdx.x * blockDim.x + threadIdx.x;
    int n = idx >> 3, q = idx & 7;
    if (n >= N) return;
    int start = rowptr[n], end = rowptr[n + 1];
    float4 as2 = *(const float4*)att_src2;
    as2.x *= kLog2e; as2.y *= kLog2e; as2.z *= kLog2e; as2.w *= kLog2e;
    float4 ad2v = *(const float4*)att_dst2;
    const float4* h4 = (const float4*)h2;
    float4 hn = h4[n];
    float ad = (hn.x * ad2v.x + hn.y * ad2v.y + hn.z * ad2v.z + hn.w * ad2v.w) * kLog2e;
    float l = 0.0f;
    float4 acc = make_float4(0.f, 0.f, 0.f, 0.f);
    int j = start + q;
    for (; j + 8 < end; j += 16) {  // two independent gathers in flight
        int s0 = ssrc[j];
        int s1 = ssrc[j + 8];
        float4 ha = h4[s0];
        float4 hb = h4[s1];
        float e0 = ha.x * as2.x + ha.y * as2.y + ha.z * as2.z + ha.w * as2.w + ad;
        float e1 = hb.x * as2.x + hb.y * as2.y + hb.z * as2.z + hb.w * as2.w + ad;
        float p0 = fexp2(leakymax(e0));
        float p1 = fexp2(leakymax(e1));
        l += p0 + p1;
        acc.x += p0 * ha.x + p1 * hb.x;
        acc.y += p0 * ha.y + p1 * hb.y;
        acc.z += p0 * ha.z + p1 * hb.z;
        acc.w += p0 * ha.w + p1 * hb.w;
    }
    if (j < end) {  // at most one tail edge per lane
        int s0 = ssrc[j];
        float4 ha = h4[s0];
        float e0 = ha.x * as2.x + ha.y * as2.y + ha.z * as2.z + ha.w * as2.w + ad;
        float p0 = fexp2(leakymax(e0));
        l += p0;
        acc.x += p0 * ha.x;
        acc.y += p0 * ha.y;
        acc.z += p0 * ha.z;
        acc.w += p0 * ha.w;
    }
#pragma unroll
    for (int off = 1; off < 8; off <<= 1) {
        l += __shfl_xor(l, off);
        acc.x += __shfl_xor(acc.x, off);
        acc.y += __shfl_xor(acc.y, off);
        acc.z += __shfl_xor(acc.z, off);
        acc.w += __shfl_xor(acc.w, off);
    }
    if (q == 0) {
        float inv = 1.0f / (l + kEps);
        float4 v = make_float4(acc.x * inv + b2[0], acc.y * inv + b2[1],
                               acc.z * inv + b2[2], acc.w * inv + b2[3]);
        float mx = fmaxf(fmaxf(v.x, v.y), fmaxf(v.z, v.w));
        float sum = __expf(v.x - mx) + __expf(v.y - mx) + __expf(v.z - mx) + __expf(v.w - mx);
        float lse = mx + logf(sum);
        ((float4*)out)[n] = make_float4(v.x - lse, v.y - lse, v.z - lse, v.w - lse);
    }
}

extern "C" void kernel_launch(void* const* d_in, const int* in_sizes, int n_in,
                              void* d_out, int out_size, void* d_ws, size_t ws_size,
                              hipStream_t stream) {
    const float* x        = (const float*)d_in[0];
    const int*   ei       = (const int*)d_in[1];
    const float* W1       = (const float*)d_in[2];
    const float* att_src1 = (const float*)d_in[3];
    const float* att_dst1 = (const float*)d_in[4];
    const float* b1       = (const float*)d_in[5];
    const float* W2       = (const float*)d_in[6];
    const float* att_src2 = (const float*)d_in[7];
    const float* att_dst2 = (const float*)d_in[8];
    const float* b2       = (const float*)d_in[9];

    const int N = in_sizes[0] / 2;           // x is [N,2]
    const int E = in_sizes[1] / 2;           // edge_index is [2,E]
    const int NBUCK = (N + BMASK) >> BSHIFT; // 128-node buckets (<= 832)
    const int ntable = NBUCK * SLICES;
    const int nsb = (ntable + 1023) / 1024;  // scan chunks

    // ---- workspace layout (4B elems); ~15.7MB proven ----
    int* table     = (int*)d_ws;                  // ntable (+64 pad)
    int* partial   = table + ntable + 64;         // nsb (pad 1024)
    int* rowptr    = partial + 1024;              // N+1 -> pad N+4
    int* ssrc      = rowptr + ((N + 4) & ~3);     // E
    unsigned* sbuf = (unsigned*)(ssrc + E);       // E (dead after k_sort)
    float* attA    = (float*)sbuf;                // N*8 floats (overlay)
    float* attB    = attA + (size_t)N * 8;        // N*8 floats
    size_t post    = (size_t)E > (size_t)N * 16 ? (size_t)E : (size_t)N * 16;
    float* h2      = (float*)(sbuf + post);       // N*4 floats

    // bucketed partition (by destination), no global atomics
    k_hist1<<<SLICES, 512, 0, stream>>>(ei, table, rowptr, E, N, NBUCK);
    k_scan_reduce<<<nsb, 256, 0, stream>>>(table, partial, ntable);
    k_scan_apply<<<nsb, 256, 0, stream>>>(table, partial, ntable, nsb);
    k_bin2<<<SLICES, 512, 0, stream>>>(ei, table, sbuf, E, NBUCK);

    // per-bucket counting sort -> CSR
    k_sort<<<NBUCK, 512, 0, stream>>>(sbuf, table, rowptr, ssrc, N, E, NBUCK);

    // layer 1: attention accumulate (lean) -> dense MLP fold
    k_gather1<<<(N * 8 + 255) / 256, 256, 0, stream>>>(rowptr, ssrc, x,
                                                       W1, att_src1, att_dst1,
                                                       attA, attB, N);
    k_fold<<<(N + 255) / 256, 256, 0, stream>>>(attA, attB, W1, b1, W2, h2, N);

    // layer 2 gather + log_softmax
    k_gather2_out<<<(N * 8 + 255) / 256, 256, 0, stream>>>(rowptr, ssrc, h2,
                                                           att_src2, att_dst2, b2,
                                                           (float*)d_out, N);
}

// Round 9
// 146.260 us; speedup vs baseline: 2.8845x; 1.0356x over previous
//
#include <hip/hip_runtime.h>
#include <math.h>

static constexpr float kNegSlope = 0.2f;
static constexpr float kEps = 1e-16f;
static constexpr float kLog2e = 1.44269504088896340736f;
static constexpr int SLICES = 256;   // R6: 512 was null -> proven 256
static constexpr int BSHIFT = 7;     // 128 nodes per bucket
static constexpr int BMASK = 127;
static constexpr unsigned SRCMASK = 0x1FFFFu;  // 17 bits (N < 131072)
static constexpr int CAP = 2816;     // LDS bucket capacity (mean 2048, +17 sigma)

// leaky(v) = fmaxf(v, 0.2v): exact identity (0.2>0).
__device__ __forceinline__ float leakymax(float v) {
    return fmaxf(v, kNegSlope * v);
}

// Raw 2^x (v_exp_f32). Projections pre-scaled by log2(e):
// 2^leaky(z*log2e) == e^leaky(z) exactly (leaky commutes with c>0 scaling).
__device__ __forceinline__ float fexp2(float v) {
#if __has_builtin(__builtin_amdgcn_exp2f)
    return __builtin_amdgcn_exp2f(v);
#else
    return exp2f(v);
#endif
}

// ================= atomic-free bucketed partition (PROVEN form) =================
// bucket = dst >> 7 (128 nodes). Per-slice private LDS histograms ->
// scan of table[bucket][slice] -> deterministic scatter with LDS cursors.
// Record: src | (d&127)<<17 (24 bits, 4B).
// LEDGER (do not retry): global-atomic node scatter = 107MB write-amp, 134us
// (R4). Edge-parallel LDS-float-atomic accumulate = same-address serialization,
// 261us (R5). SLICES=512 = null (R6). Gather kernels: streaming==gather (R0),
// wide MLP batch regresses via VGPR (R1), lane remap null (R3), -25% VALU ops
// null (R7) -> gathers are chain-latency bound, not issue/memory bound.

__global__ __launch_bounds__(512) void k_hist1(const int* __restrict__ ei,
                                               int* __restrict__ table,
                                               int* __restrict__ rowptr,
                                               float* __restrict__ pbufG,
                                               const float* __restrict__ W1,
                                               const float* __restrict__ att_src1,
                                               const float* __restrict__ att_dst1,
                                               int E, int N, int NBUCK) {
    __shared__ int hist[832];
    int b = blockIdx.x, t = threadIdx.x;
    if (b == 0 && t == 0) rowptr[N] = E;  // sentinel
    if (b == 0 && t < 32) {
        // rank-2 projections, PRE-SCALED by log2(e) — hoisted out of k_gather1
        // (was a ~600cy prologue+barrier in all 3125 gather1 blocks)
        int which = t >> 4;   // 0=src, 1=dst
        int hd = t & 15;
        int h = hd >> 1, d = hd & 1;
        const float* att = which ? att_dst1 : att_src1;
        float s = 0.0f;
#pragma unroll
        for (int c = 0; c < 16; ++c) s += W1[d * 128 + h * 16 + c] * att[h * 16 + c];
        pbufG[which * 16 + d * 8 + h] = s * kLog2e;
    }
    for (int i = t; i < NBUCK; i += 512) hist[i] = 0;
    __syncthreads();
    int S = (((E + SLICES - 1) / SLICES) + 3) & ~3;  // slice size, multiple of 4
    int lo = b * S, hi = min(lo + S, E);
    for (int i = lo + t * 4; i < hi; i += 512 * 4) {
        int4 dv = *(const int4*)(ei + E + i);
        atomicAdd(&hist[dv.x >> BSHIFT], 1);
        atomicAdd(&hist[dv.y >> BSHIFT], 1);
        atomicAdd(&hist[dv.z >> BSHIFT], 1);
        atomicAdd(&hist[dv.w >> BSHIFT], 1);
    }
    __syncthreads();
    for (int i = t; i < NBUCK; i += 512) table[i * SLICES + b] = hist[i];
}

// Scan pass 1: block b sums its 1024-int chunk -> partial[b].
__global__ __launch_bounds__(256) void k_scan_reduce(const int* __restrict__ src,
                                                     int* __restrict__ partial, int n) {
    __shared__ int wsum[4];
    int b = blockIdx.x, t = threadIdx.x;
    int base = b * 1024 + t * 4;
    int s = 0;
#pragma unroll
    for (int k = 0; k < 4; ++k) {
        int idx = base + k;
        s += (idx < n) ? src[idx] : 0;
    }
#pragma unroll
    for (int off = 1; off < 64; off <<= 1) s += __shfl_xor(s, off);
    if ((t & 63) == 0) wsum[t >> 6] = s;
    __syncthreads();
    if (t == 0) partial[b] = wsum[0] + wsum[1] + wsum[2] + wsum[3];
}

// Scan pass 2: block b computes its chunk base by reducing partial[i<b],
// then wave-scans its 1024-int chunk in place (exclusive).
__global__ __launch_bounds__(256) void k_scan_apply(int* __restrict__ data,
                                                    const int* __restrict__ partial,
                                                    int n, int nsb) {
    __shared__ int sm[8];
    __shared__ int baseSh;
    int b = blockIdx.x, t = threadIdx.x;
    int acc = 0;
    for (int i = t; i < b; i += 256) acc += partial[i];
#pragma unroll
    for (int off = 1; off < 64; off <<= 1) acc += __shfl_xor(acc, off);
    if ((t & 63) == 0) sm[t >> 6] = acc;
    __syncthreads();
    if (t == 0) baseSh = sm[0] + sm[1] + sm[2] + sm[3];
    __syncthreads();
    int chunkBase = baseSh;
    __syncthreads();  // sm reused below
    int base = b * 1024 + t * 4;
    int v[4];
#pragma unroll
    for (int k = 0; k < 4; ++k) {
        int idx = base + k;
        v[k] = (idx < n) ? data[idx] : 0;
    }
    int sum4 = v[0] + v[1] + v[2] + v[3];
    int s = sum4;
#pragma unroll
    for (int off = 1; off < 64; off <<= 1) {
        int u = __shfl_up(s, off);
        if ((t & 63) >= off) s += u;
    }
    if ((t & 63) == 63) sm[t >> 6] = s;
    __syncthreads();
    int woff = 0;
    int w = t >> 6;
    for (int ww = 0; ww < w; ++ww) woff += sm[ww];
    int ex = chunkBase + woff + (s - sum4);
#pragma unroll
    for (int k = 0; k < 4; ++k) {
        int idx = base + k;
        if (idx < n) data[idx] = ex;
        ex += v[k];
    }
}

__global__ __launch_bounds__(512) void k_bin2(const int* __restrict__ ei,
                                              const int* __restrict__ table,
                                              unsigned* __restrict__ sbuf, int E, int NBUCK) {
    __shared__ int cur[832];
    int b = blockIdx.x, t = threadIdx.x;
    for (int i = t; i < NBUCK; i += 512) cur[i] = table[i * SLICES + b];
    __syncthreads();
    int S = (((E + SLICES - 1) / SLICES) + 3) & ~3;
    int lo = b * S, hi = min(lo + S, E);
    for (int i = lo + t * 4; i < hi; i += 512 * 4) {
        int4 sv = *(const int4*)(ei + i);
        int4 dv = *(const int4*)(ei + E + i);
        int pos;
        pos = atomicAdd(&cur[dv.x >> BSHIFT], 1);
        sbuf[pos] = (unsigned)sv.x | ((unsigned)(dv.x & BMASK) << 17);
        pos = atomicAdd(&cur[dv.y >> BSHIFT], 1);
        sbuf[pos] = (unsigned)sv.y | ((unsigned)(dv.y & BMASK) << 17);
        pos = atomicAdd(&cur[dv.z >> BSHIFT], 1);
        sbuf[pos] = (unsigned)sv.z | ((unsigned)(dv.z & BMASK) << 17);
        pos = atomicAdd(&cur[dv.w >> BSHIFT], 1);
        sbuf[pos] = (unsigned)sv.w | ((unsigned)(dv.w & BMASK) << 17);
    }
}

// ================= per-bucket counting sort -> CSR =================
__global__ __launch_bounds__(512) void k_sort(
        const unsigned* __restrict__ sbuf, const int* __restrict__ table,
        int* __restrict__ rowptr, int* __restrict__ ssrc,
        int N, int E, int NBUCK) {
    __shared__ int hist[128];
    __shared__ int sc[128];
    __shared__ int cur[128];
    __shared__ unsigned raws[CAP];
    __shared__ int sls[CAP];
    int b = blockIdx.x;
    int t = threadIdx.x;
    int lo = table[b * SLICES];
    int hi = (b + 1 < NBUCK) ? table[(b + 1) * SLICES] : E;
    int cnt = hi - lo;
    bool inLds = (cnt <= CAP);

    if (t < 128) hist[t] = 0;
    __syncthreads();

    if (inLds) {
        for (int i = t; i < cnt; i += 512) {
            unsigned v = sbuf[lo + i];
            raws[i] = v;
            atomicAdd(&hist[v >> 17], 1);
        }
    } else {
        for (int i = lo + t; i < hi; i += 512) atomicAdd(&hist[sbuf[i] >> 17], 1);
    }
    __syncthreads();

    if (t < 128) {  // two-wave shfl inclusive scan of 128 bins
        int lane = t & 63;
        int own = hist[t];
        int v = own;
#pragma unroll
        for (int off = 1; off < 64; off <<= 1) {
            int u = __shfl_up(v, off);
            if (lane >= off) v += u;
        }
        sc[t] = v;
    }
    __syncthreads();
    if (t < 128) {
        int ex = sc[t] - hist[t] + (t >= 64 ? sc[63] : 0);
        cur[t] = ex;
        int node = (b << BSHIFT) + t;
        if (node < N) rowptr[node] = lo + ex;
    }
    __syncthreads();

    if (inLds) {
        for (int i = t; i < cnt; i += 512) {
            unsigned v = raws[i];
            int pos = atomicAdd(&cur[v >> 17], 1);
            sls[pos] = (int)(v & SRCMASK);
        }
        __syncthreads();
        for (int i = t; i < cnt; i += 512) ssrc[lo + i] = sls[i];  // coalesced
    } else {  // overflow fallback (statistically never: mean 2048, CAP 2816)
        for (int i = lo + t; i < hi; i += 512) {
            unsigned v = sbuf[i];
            int pos = atomicAdd(&cur[v >> 17], 1);
            ssrc[lo + pos] = (int)(v & SRCMASK);
        }
    }
}

// ================= layer 1 attention accumulate (node-parallel) =================
// 8 lanes/node. R8: ssrc PREFETCH ROTATION — each round prefetches the next
// round's ssrc pair before computing, taking ssrc off the serial chain:
// lifetime 2*(Ls+Lx) -> Ls+2*Lx. Second-edge validity via mask multiply
// (mask VALU is free — R7). pbuf loaded from global (hoisted to k_hist1).
// Straight-line softmax (no max): inputs N(0,1)-scale, |e|<~8.
__global__ __launch_bounds__(256) void k_gather1(
        const int* __restrict__ rowptr, const int* __restrict__ ssrc,
        const float* __restrict__ x, const float* __restrict__ pbufG,
        float* __restrict__ attAB, int N) {
    __shared__ float pbuf[32];  // Ps d0 | Ps d1 | Pd d0 | Pd d1 (8 heads each)
    int t = threadIdx.x;
    if (t < 32) pbuf[t] = pbufG[t];
    __syncthreads();

    int idx = blockIdx.x * blockDim.x + t;
    int n = idx >> 3, q = idx & 7;
    if (n >= N) return;
    const float2* x2 = (const float2*)x;
    int start = rowptr[n], end = rowptr[n + 1];
    float2 xn = x2[n];
    float Ps0[8], Ps1[8], adv[8], l[8], s0[8], s1[8];
#pragma unroll
    for (int h = 0; h < 8; ++h) {
        Ps0[h] = pbuf[h];
        Ps1[h] = pbuf[8 + h];
        adv[h] = xn.x * pbuf[16 + h] + xn.y * pbuf[24 + h];
        l[h] = 0.f; s0[h] = 0.f; s1[h] = 0.f;
    }
    int j = start + q;
    if (j < end) {
        int safe = end - 1;  // >= 0 here (end > j >= 0)
        int sa = ssrc[j];
        int sb = ssrc[min(j + 8, safe)];
        while (true) {
            int j2 = j + 16;
            int sa2 = ssrc[min(j2, safe)];      // prefetch next round
            int sb2 = ssrc[min(j2 + 8, safe)];
            float2 xa = x2[sa];
            float2 xb = x2[sb];
            float mB = (j + 8 < end) ? 1.0f : 0.0f;
#pragma unroll
            for (int h = 0; h < 8; ++h) {
                float pa = fexp2(leakymax(fmaf(xa.x, Ps0[h], fmaf(xa.y, Ps1[h], adv[h]))));
                float pb = fexp2(leakymax(fmaf(xb.x, Ps0[h], fmaf(xb.y, Ps1[h], adv[h])))) * mB;
                l[h] += pa + pb;
                s0[h] = fmaf(pa, xa.x, fmaf(pb, xb.x, s0[h]));
                s1[h] = fmaf(pa, xa.y, fmaf(pb, xb.y, s1[h]));
            }
            if (j2 >= end) break;
            j = j2; sa = sa2; sb = sb2;
        }
    }
#pragma unroll
    for (int off = 1; off < 8; off <<= 1) {
#pragma unroll
        for (int h = 0; h < 8; ++h) {
            l[h] += __shfl_xor(l[h], off);
            s0[h] += __shfl_xor(s0[h], off);
            s1[h] += __shfl_xor(s1[h], off);
        }
    }
    // lane q emits head q's normalized pair: ONE 8B interleaved store
    float inv = 1.0f / (l[q] + kEps);
    ((float2*)attAB)[n * 8 + q] = make_float2(s0[q] * inv, s1[q] * inv);
}

// ================= dense per-node MLP: W1 -> relu -> W2 =================
// 1 thread/node. attAB interleaved: per node 16 floats = h0(s0,s1), h1(s0,s1)...
__global__ __launch_bounds__(256) void k_fold(
        const float* __restrict__ attAB,
        const float* __restrict__ W1, const float* __restrict__ b1,
        const float* __restrict__ W2, float* __restrict__ h2, int N) {
    __shared__ float4 pk1[128];  // (W1a, W1b, b1, 0) per col
    __shared__ float4 pk2[128];  // W2 row per col
    int t = threadIdx.x;
    if (t < 128) {
        pk1[t] = make_float4(W1[t], W1[128 + t], b1[t], 0.f);
        pk2[t] = ((const float4*)W2)[t];
    }
    __syncthreads();
    int n = blockIdx.x * 256 + t;
    if (n >= N) return;
    const float4* AB = (const float4*)(attAB + (size_t)n * 16);
    float4 r0 = AB[0], r1 = AB[1], r2 = AB[2], r3 = AB[3];
    float4 acc = make_float4(0.f, 0.f, 0.f, 0.f);
#pragma unroll
    for (int h = 0; h < 8; ++h) {  // ternaries fold at compile time
        float sx0 = (h == 0) ? r0.x : (h == 1) ? r0.z : (h == 2) ? r1.x :
                    (h == 3) ? r1.z : (h == 4) ? r2.x : (h == 5) ? r2.z :
                    (h == 6) ? r3.x : r3.z;
        float sx1 = (h == 0) ? r0.y : (h == 1) ? r0.w : (h == 2) ? r1.y :
                    (h == 3) ? r1.w : (h == 4) ? r2.y : (h == 5) ? r2.w :
                    (h == 6) ? r3.y : r3.w;
#pragma unroll
        for (int c = 0; c < 16; ++c) {
            int col = h * 16 + c;
            float4 p = pk1[col];
            float o = fmaxf(p.x * sx0 + p.y * sx1 + p.z, 0.0f);
            float4 w = pk2[col];
            acc.x += o * w.x;
            acc.y += o * w.y;
            acc.z += o * w.z;
            acc.w += o * w.w;
        }
    }
    ((float4*)h2)[n] = acc;
}

// ================= layer 2 gather + log_softmax =================
// 8 lanes/node; R8 ssrc prefetch rotation (same chain surgery as k_gather1).
__global__ __launch_bounds__(256) void k_gather2_out(
        const int* __restrict__ rowptr, const int* __restrict__ ssrc,
        const float* __restrict__ h2, const float* __restrict__ att_src2,
        const float* __restrict__ att_dst2, const float* __restrict__ b2,
        float* __restrict__ out, int N) {
    int idx = blockIdx.x * blockDim.x + threadIdx.x;
    int n = idx >> 3, q = idx & 7;
    if (n >= N) return;
    int start = rowptr[n], end = rowptr[n + 1];
    float4 as2 = *(const float4*)att_src2;
    as2.x *= kLog2e; as2.y *= kLog2e; as2.z *= kLog2e; as2.w *= kLog2e;
    float4 ad2v = *(const float4*)att_dst2;
    const float4* h4 = (const float4*)h2;
    float4 hn = h4[n];
    float ad = (hn.x * ad2v.x + hn.y * ad2v.y + hn.z * ad2v.z + hn.w * ad2v.w) * kLog2e;
    float l = 0.0f;
    float4 acc = make_float4(0.f, 0.f, 0.f, 0.f);
    int j = start + q;
    if (j < end) {
        int safe = end - 1;
        int sa = ssrc[j];
        int sb = ssrc[min(j + 8, safe)];
        while (true) {
            int j2 = j + 16;
            int sa2 = ssrc[min(j2, safe)];      // prefetch next round
            int sb2 = ssrc[min(j2 + 8, safe)];
            float4 ha = h4[sa];
            float4 hb = h4[sb];
            float mB = (j + 8 < end) ? 1.0f : 0.0f;
            float e0 = ha.x * as2.x + ha.y * as2.y + ha.z * as2.z + ha.w * as2.w + ad;
            float e1 = hb.x * as2.x + hb.y * as2.y + hb.z * as2.z + hb.w * as2.w + ad;
            float p0 = fexp2(leakymax(e0));
            float p1 = fexp2(leakymax(e1)) * mB;
            l += p0 + p1;
            acc.x += p0 * ha.x + p1 * hb.x;
            acc.y += p0 * ha.y + p1 * hb.y;
            acc.z += p0 * ha.z + p1 * hb.z;
            acc.w += p0 * ha.w + p1 * hb.w;
            if (j2 >= end) break;
            j = j2; sa = sa2; sb = sb2;
        }
    }
#pragma unroll
    for (int off = 1; off < 8; off <<= 1) {
        l += __shfl_xor(l, off);
        acc.x += __shfl_xor(acc.x, off);
        acc.y += __shfl_xor(acc.y, off);
        acc.z += __shfl_xor(acc.z, off);
        acc.w += __shfl_xor(acc.w, off);
    }
    if (q == 0) {
        float inv = 1.0f / (l + kEps);
        float4 v = make_float4(acc.x * inv + b2[0], acc.y * inv + b2[1],
                               acc.z * inv + b2[2], acc.w * inv + b2[3]);
        float mx = fmaxf(fmaxf(v.x, v.y), fmaxf(v.z, v.w));
        float sum = __expf(v.x - mx) + __expf(v.y - mx) + __expf(v.z - mx) + __expf(v.w - mx);
        float lse = mx + logf(sum);
        ((float4*)out)[n] = make_float4(v.x - lse, v.y - lse, v.z - lse, v.w - lse);
    }
}

extern "C" void kernel_launch(void* const* d_in, const int* in_sizes, int n_in,
                              void* d_out, int out_size, void* d_ws, size_t ws_size,
                              hipStream_t stream) {
    const float* x        = (const float*)d_in[0];
    const int*   ei       = (const int*)d_in[1];
    const float* W1       = (const float*)d_in[2];
    const float* att_src1 = (const float*)d_in[3];
    const float* att_dst1 = (const float*)d_in[4];
    const float* b1       = (const float*)d_in[5];
    const float* W2       = (const float*)d_in[6];
    const float* att_src2 = (const float*)d_in[7];
    const float* att_dst2 = (const float*)d_in[8];
    const float* b2       = (const float*)d_in[9];

    const int N = in_sizes[0] / 2;           // x is [N,2]
    const int E = in_sizes[1] / 2;           // edge_index is [2,E]
    const int NBUCK = (N + BMASK) >> BSHIFT; // 128-node buckets (<= 832)
    const int ntable = NBUCK * SLICES;
    const int nsb = (ntable + 1023) / 1024;  // scan chunks

    // ---- workspace layout (4B elems); ~15.7MB proven ----
    int* table     = (int*)d_ws;                  // ntable (+64 pad)
    int* partial   = table + ntable + 64;         // nsb (pad 1024)
    float* pbufG   = (float*)(partial + 1024);    // 32 floats (pad 64)
    int* rowptr    = partial + 1024 + 64;         // N+1 -> pad N+4
    int* ssrc      = rowptr + ((N + 4) & ~3);     // E
    unsigned* sbuf = (unsigned*)(ssrc + E);       // E (dead after k_sort)
    float* attAB   = (float*)sbuf;                // N*16 floats (overlay)
    size_t post    = (size_t)E > (size_t)N * 16 ? (size_t)E : (size_t)N * 16;
    float* h2      = (float*)(sbuf + post);       // N*4 floats

    // bucketed partition (by destination), no global atomics
    k_hist1<<<SLICES, 512, 0, stream>>>(ei, table, rowptr, pbufG,
                                        W1, att_src1, att_dst1, E, N, NBUCK);
    k_scan_reduce<<<nsb, 256, 0, stream>>>(table, partial, ntable);
    k_scan_apply<<<nsb, 256, 0, stream>>>(table, partial, ntable, nsb);
    k_bin2<<<SLICES, 512, 0, stream>>>(ei, table, sbuf, E, NBUCK);

    // per-bucket counting sort -> CSR
    k_sort<<<NBUCK, 512, 0, stream>>>(sbuf, table, rowptr, ssrc, N, E, NBUCK);

    // layer 1: attention accumulate (prefetch-rotated) -> dense MLP fold
    k_gather1<<<(N * 8 + 255) / 256, 256, 0, stream>>>(rowptr, ssrc, x, pbufG,
                                                       attAB, N);
    k_fold<<<(N + 255) / 256, 256, 0, stream>>>(attAB, W1, b1, W2, h2, N);

    // layer 2 gather + log_softmax (prefetch-rotated)
    k_gather2_out<<<(N * 8 + 255) / 256, 256, 0, stream>>>(rowptr, ssrc, h2,
                                                           att_src2, att_dst2, b2,
                                                           (float*)d_out, N);
}